// Round 4
// baseline (984.702 us; speedup 1.0000x reference)
//
#include <hip/hip_runtime.h>

typedef __attribute__((ext_vector_type(8))) short short8;
typedef __attribute__((ext_vector_type(4))) float f32x4;
typedef __attribute__((ext_vector_type(2))) unsigned int uint2v;
typedef unsigned short u16;
typedef unsigned int u32;

// ---------- d_ws layout (u16 elements), all transposed: wT[n][k] = W[k][n] ----------
#define WT1_OFF 0                      // [128][72]   d1_W0^T  K=64 (63 + zero pad)
#define WT2_OFF (WT1_OFF + 128*72)     // [128][136]  d1_W1^T  K=128
#define WT3_OFF (WT2_OFF + 128*136)    // [128][136]  d1_W2^T
#define WT4_OFF (WT3_OFF + 128*136)    // [128][200]  d2_W0^T  K=192 (63 pos + zero + 128 hidden)
#define WT5_OFF (WT4_OFF + 128*200)    // [128][136]  d2_W1^T
#define WT6_OFF (WT5_OFF + 128*136)    // [128][136]  d2_W2^T
#define WT7_OFF (WT6_OFF + 128*136)    // [144][136]  d2_W3^T  n<128: col n+1 (feature); n==128: col 0 (density)
#define WT8_OFF (WT7_OFF + 144*136)    // [128][168]  c_W0^T   K=160 (27 view + 5 zero + 128 feature)
#define WT9_OFF (WT8_OFF + 128*168)    // [16][136]   c_W1^T   n<3: rgb, rest zero
#define WS_ELEMS (WT9_OFF + 16*136)    // = 147712 u16 = 295424 B
#define WS_FLAG_OFF WS_ELEMS           // u32 dtype flag (4B aligned)

__device__ __forceinline__ u16 f2bf(float f) {
  u32 u = __builtin_bit_cast(u32, f);
  u += 0x7fffu + ((u >> 16) & 1u);   // RNE
  return (u16)(u >> 16);
}

// fp32-vs-bf16 input detection (kept for robustness; r1->r2 NaN->finite flip
// proved the weights are fp32 on this dataset).
__device__ __forceinline__ bool detect_fp32(const void* w) {
  const u32* p = (const u32*)w;
  int in_range = 0;
#pragma unroll 8
  for (int i = 0; i < 64; ++i) {
    u32 v = p[i];
    int e0 = (v >> 7) & 0xff;
    int e1 = (v >> 23) & 0xff;
    in_range += (e0 >= 100 && e0 <= 132) ? 1 : 0;
    in_range += (e1 >= 100 && e1 <= 132) ? 1 : 0;
  }
  return in_range < 102;
}

__device__ __forceinline__ u16 ldw(const void* p, long long idx, bool fp32) {
  if (fp32) return f2bf(((const float*)p)[idx]);
  return ((const u16*)p)[idx];
}

// ---------------- weight prep: transpose + pad into d_ws (runs every launch) ----------------
extern "C" __global__ void nerf_prep(
    const void* __restrict__ d1W0, const void* __restrict__ d1W1, const void* __restrict__ d1W2,
    const void* __restrict__ d2W0, const void* __restrict__ d2W1, const void* __restrict__ d2W2,
    const void* __restrict__ d2W3, const void* __restrict__ cW0,  const void* __restrict__ cW1,
    u16* __restrict__ ws)
{
  const bool fp32 = detect_fp32(d1W0);
  int t = blockIdx.x * blockDim.x + threadIdx.x;
  int T = gridDim.x * blockDim.x;
  if (t == 0) *(u32*)(ws + WS_FLAG_OFF) = fp32 ? 1u : 0u;

  for (int i = t; i < 128*72; i += T) {
    int n = i / 72, k = i % 72;
    ws[WT1_OFF + i] = (k < 63) ? ldw(d1W0, k*128 + n, fp32) : (u16)0;
  }
  for (int i = t; i < 128*136; i += T) {
    int n = i / 136, k = i % 136;
    u16 a = 0, b = 0, c = 0, d = 0;
    if (k < 128) {
      a = ldw(d1W1, k*128+n, fp32); b = ldw(d1W2, k*128+n, fp32);
      c = ldw(d2W1, k*128+n, fp32); d = ldw(d2W2, k*128+n, fp32);
    }
    ws[WT2_OFF + i] = a; ws[WT3_OFF + i] = b; ws[WT5_OFF + i] = c; ws[WT6_OFF + i] = d;
  }
  for (int i = t; i < 128*200; i += T) {
    int n = i / 200, k = i % 200;
    u16 v = 0;
    if (k < 63) v = ldw(d2W0, k*128 + n, fp32);
    else if (k >= 64 && k < 192) v = ldw(d2W0, (k-1)*128 + n, fp32);
    ws[WT4_OFF + i] = v;
  }
  for (int i = t; i < 144*136; i += T) {
    int n = i / 136, k = i % 136;
    u16 v = 0;
    if (k < 128) {
      if (n < 128) v = ldw(d2W3, k*129 + n + 1, fp32);
      else if (n == 128) v = ldw(d2W3, k*129, fp32);
    }
    ws[WT7_OFF + i] = v;
  }
  for (int i = t; i < 128*168; i += T) {
    int n = i / 168, k = i % 168;
    u16 v = 0;
    if (k < 27) v = ldw(cW0, k*128 + n, fp32);
    else if (k >= 32 && k < 160) v = ldw(cW0, (k-5)*128 + n, fp32);
    ws[WT8_OFF + i] = v;
  }
  for (int i = t; i < 16*136; i += T) {
    int n = i / 136, k = i % 136;
    ws[WT9_OFF + i] = (n < 3 && k < 128) ? ldw(cW1, k*3 + n, fp32) : (u16)0;
  }
}

// ---------------- fused MLP ----------------
// MFMA scheme: D = A*B, A = W^T tile (first operand: lane&15 indexes out-channel,
// k = quad*8+j), B = act tile (second operand: lane&15 indexes batch row).
// D-frag (m89 layout): col(lane&15) = batch row, row(quad*4+reg) = out channel ->
// 4 consecutive channels per lane -> one 8B LDS write; activations stay
// row-major [row][ch] for the next layer's B-frag ds_read_b128.

template<int NT, int KS0, int KS1>
__device__ __forceinline__ void run_layer(
    f32x4 (&acc)[4][5],
    const u16* __restrict__ wT, const int wstride,
    const u16* s0, const int s0stride,
    const u16* s1, const int s1stride,
    const int ln, const int kq8, const int m0, const int n0)
{
#pragma unroll
  for (int mi = 0; mi < 4; ++mi)
#pragma unroll
    for (int ni = 0; ni < NT; ++ni)
      acc[mi][ni] = f32x4{0.f, 0.f, 0.f, 0.f};

#pragma unroll
  for (int ks = 0; ks < KS0 + KS1; ++ks) {
    const u16* src = (ks < KS0) ? s0 : s1;
    const int sstride = (ks < KS0) ? s0stride : s1stride;
    const int klocal  = (ks < KS0) ? ks*32 : (ks - KS0)*32;
    const int kw = ks*32 + kq8;
    short8 a[NT], b[4];
#pragma unroll
    for (int ni = 0; ni < NT; ++ni)
      a[ni] = *(const short8*)(wT + (n0 + 16*ni + ln) * wstride + kw);
#pragma unroll
    for (int mi = 0; mi < 4; ++mi)
      b[mi] = *(const short8*)(src + (m0 + 16*mi + ln) * sstride + klocal + kq8);
#pragma unroll
    for (int mi = 0; mi < 4; ++mi)
#pragma unroll
      for (int ni = 0; ni < NT; ++ni)
        acc[mi][ni] = __builtin_amdgcn_mfma_f32_16x16x32_bf16(a[ni], b[mi], acc[mi][ni], 0, 0, 0);
  }
}

template<bool RELU>
__device__ __forceinline__ void store_act(
    const f32x4 (&acc)[4][5], u16* dst, const int dstride,
    const int ln, const int kq, const int m0, const int n0)
{
#pragma unroll
  for (int mi = 0; mi < 4; ++mi)
#pragma unroll
    for (int ni = 0; ni < 4; ++ni) {
      const int m  = m0 + 16*mi + ln;
      const int nb = n0 + 16*ni + 4*kq;
      f32x4 v = acc[mi][ni];
      float v0 = RELU ? fmaxf(v[0], 0.f) : v[0];
      float v1 = RELU ? fmaxf(v[1], 0.f) : v[1];
      float v2 = RELU ? fmaxf(v[2], 0.f) : v[2];
      float v3 = RELU ? fmaxf(v[3], 0.f) : v[3];
      uint2v o;
      o[0] = (u32)f2bf(v0) | ((u32)f2bf(v1) << 16);
      o[1] = (u32)f2bf(v2) | ((u32)f2bf(v3) << 16);
      *(uint2v*)(dst + m * dstride + nb) = o;   // 8B ds_write_b64
    }
}

extern "C" __global__ void __launch_bounds__(256, 2) nerf_main(
    const void* __restrict__ xv, const u16* __restrict__ ws, float* __restrict__ out)
{
  __shared__ u16 in_s[128][104];   // pos ch 0..62 at [0..62], [63]=0; view ch v at [64+v] (64..90), [91..95]=0
  __shared__ u16 act_s[128][136];  // current 128-wide activation, +8 pad
  __shared__ float dens_s[128];

  const int tid  = threadIdx.x;
  const int lane = tid & 63;
  const int wv   = tid >> 6;        // 4 waves
  const int ln   = lane & 15;
  const int kq   = lane >> 4;
  const int kq8  = kq * 8;
  const int m0   = (wv >> 1) * 64;  // row-tile range of this wave
  const int n0   = (wv & 1) * 64;   // channel-tile range
  const long long row0 = (long long)blockIdx.x * 128;

  // zero pad columns
  if (tid < 128) {
    in_s[tid][63] = 0;
    in_s[tid][91] = 0; in_s[tid][92] = 0; in_s[tid][93] = 0;
    in_s[tid][94] = 0; in_s[tid][95] = 0;
  }
  // stage x, dtype-dependent
  {
    const u32 fp32flag = *(const u32*)(ws + WS_FLAG_OFF);
    if (fp32flag) {
      const u32* x32 = (const u32*)xv;
      for (int i = tid; i < 90*128; i += 256) {
        int r = i / 90, c = i - r*90;
        u32 v = x32[(row0 + r) * 90LL + c];
        in_s[r][c + (c >= 63)] = f2bf(__builtin_bit_cast(float, v));
      }
    } else {
      const u32* x32 = (const u32*)xv;
      for (int i = tid; i < 45*128; i += 256) {
        int r = i / 45, c2 = i - r*45;
        u32 v = x32[(row0 + r) * 45LL + c2];
        int c0 = 2*c2, c1 = c0 + 1;
        in_s[r][c0 + (c0 >= 63)] = (u16)(v & 0xffffu);
        in_s[r][c1 + (c1 >= 63)] = (u16)(v >> 16);
      }
    }
  }
  __syncthreads();

  f32x4 acc[4][5];
  const u16* wT1 = ws + WT1_OFF;  const u16* wT2 = ws + WT2_OFF;
  const u16* wT3 = ws + WT3_OFF;  const u16* wT4 = ws + WT4_OFF;
  const u16* wT5 = ws + WT5_OFF;  const u16* wT6 = ws + WT6_OFF;
  const u16* wT7 = ws + WT7_OFF;  const u16* wT8 = ws + WT8_OFF;
  const u16* wT9 = ws + WT9_OFF;
  const u16* inb  = &in_s[0][0];
  const u16* vwb  = &in_s[0][64];
  u16* actb = &act_s[0][0];

  // L1: relu(pos @ d1_W0)
  run_layer<4,2,0>(acc, wT1, 72, inb, 104, nullptr, 0, ln, kq8, m0, n0);
  store_act<true>(acc, actb, 136, ln, kq, m0, n0);
  __syncthreads();

  // L2
  run_layer<4,4,0>(acc, wT2, 136, actb, 136, nullptr, 0, ln, kq8, m0, n0);
  __syncthreads();
  store_act<true>(acc, actb, 136, ln, kq, m0, n0);
  __syncthreads();

  // L3: part1
  run_layer<4,4,0>(acc, wT3, 136, actb, 136, nullptr, 0, ln, kq8, m0, n0);
  __syncthreads();
  store_act<true>(acc, actb, 136, ln, kq, m0, n0);
  __syncthreads();

  // L4: relu([pos, part1] @ d2_W0)
  run_layer<4,2,4>(acc, wT4, 200, inb, 104, actb, 136, ln, kq8, m0, n0);
  __syncthreads();
  store_act<true>(acc, actb, 136, ln, kq, m0, n0);
  __syncthreads();

  // L5
  run_layer<4,4,0>(acc, wT5, 136, actb, 136, nullptr, 0, ln, kq8, m0, n0);
  __syncthreads();
  store_act<true>(acc, actb, 136, ln, kq, m0, n0);
  __syncthreads();

  // L6
  run_layer<4,4,0>(acc, wT6, 136, actb, 136, nullptr, 0, ln, kq8, m0, n0);
  __syncthreads();
  store_act<true>(acc, actb, 136, ln, kq, m0, n0);
  __syncthreads();

  // L7: out2 (NO relu); odd waves also density tile
  if (wv & 1)
    run_layer<5,4,0>(acc, wT7, 136, actb, 136, nullptr, 0, ln, kq8, m0, n0);
  else
    run_layer<4,4,0>(acc, wT7, 136, actb, 136, nullptr, 0, ln, kq8, m0, n0);
  __syncthreads();
  store_act<false>(acc, actb, 136, ln, kq, m0, n0);   // features (cols 1..128 of out2)
  if ((wv & 1) && kq == 0) {
#pragma unroll
    for (int mi = 0; mi < 4; ++mi)
      dens_s[m0 + 16*mi + ln] = acc[mi][4][0];        // density, fp32, no relu
  }
  __syncthreads();

  // L8: relu([view, feature] @ c_W0)
  run_layer<4,1,4>(acc, wT8, 168, vwb, 104, actb, 136, ln, kq8, m0, n0);
  __syncthreads();
  store_act<true>(acc, actb, 136, ln, kq, m0, n0);
  __syncthreads();

  // L9: rgb (even waves), fused with density -> FP32 output, one float4 per row
  if (!(wv & 1)) {
    run_layer<1,4,0>(acc, wT9, 136, actb, 136, nullptr, 0, ln, kq8, m0, 0);
    if (kq == 0) {
#pragma unroll
      for (int mi = 0; mi < 4; ++mi) {
        const int m = m0 + 16*mi + ln;
        f32x4 v = acc[mi][0];
        f32x4 o = {v[0], v[1], v[2], dens_s[m]};
        *(f32x4*)(out + (row0 + m) * 4) = o;   // global_store_dwordx4
      }
    }
  }
}

extern "C" void kernel_launch(void* const* d_in, const int* in_sizes, int n_in,
                              void* d_out, int out_size, void* d_ws, size_t ws_size,
                              hipStream_t stream)
{
  u16* ws   = (u16*)d_ws;
  float* out = (float*)d_out;
  const int N = in_sizes[0] / 90;           // 1048576

  nerf_prep<<<160, 256, 0, stream>>>(d_in[1], d_in[2], d_in[3], d_in[4], d_in[5],
                                     d_in[6], d_in[7], d_in[8], d_in[9], ws);
  nerf_main<<<N / 128, 256, 0, stream>>>(d_in[0], ws, out);
}